// Round 10
// baseline (216.883 us; speedup 1.0000x reference)
//
#include <hip/hip_runtime.h>
#include <math.h>

// critic_attention, round 10: round-8 structure (rolled agent loop, depth-1
// rolling prefetch, 1-wave blocks) + the register-neutral round-9 wins:
//  (a) A-operand single fp16 (weights stay hi/lo split): D = Ah*Bl + Ah*Bh.
//      Removes per-agent split8 (~32 VALU) and 2 of 6 phase-A MFMAs per ct.
//  (b) biases folded into MFMA accumulator init (D row-invariant splat).
//  (c) __launch_bounds__(64, 4): VGPR hard cap 128 (round 9's 240-VGPR balloon
//      from full unroll was the regression; round 8 compiled to 100).
//
// Fragment conventions (m89-verified, validated rounds 6-9):
//   A-frag: lane holds row (l&15), k = (l>>4)*8 + e
//   B-frag: lane holds col (l&15), k = (l>>4)*8 + e
//   D:      lane holds col (l&15), row = (l>>4)*4 + reg
//
// ws layout (halfs): W0h@0[2][4][4][16][8] W0l@4096 | W2h@8192[4][8][4][16][8]
//   W2l@24576 | W3h@40960 W3l@57344.  Total 73728 halfs = 147456 B.

#define SLOPE 0.01f
#define LOG2E 1.4426950408889634f

typedef _Float16 f16x8 __attribute__((ext_vector_type(8)));
typedef float f32x4 __attribute__((ext_vector_type(4)));

#define MFMA(a, b, c) __builtin_amdgcn_mfma_f32_16x16x32_f16((a), (b), (c), 0, 0, 0)

__device__ __forceinline__ float lrelu(float x) { return fmaxf(x, SLOPE * x); }

__device__ __forceinline__ float fast_tanh(float x) {
    float e = exp2f(x * (2.0f * LOG2E));
    float r = __fdividef(1.0f, e + 1.0f);
    return fmaf(-2.0f, r, 1.0f);
}

__device__ __forceinline__ f16x8 cvt8(const float f[8]) {
    f16x8 r;
#pragma unroll
    for (int e = 0; e < 8; ++e) r[e] = (_Float16)f[e];
    return r;
}

__device__ __forceinline__ void split8(const float f[8], f16x8& hi, f16x8& lo) {
#pragma unroll
    for (int e = 0; e < 8; ++e) {
        _Float16 h = (_Float16)f[e];
        hi[e] = h;
        lo[e] = (_Float16)(f[e] - (float)h);
    }
}

// ---------------- prep: split weights into per-lane fp16 hi/lo fragments ----------------
__global__ __launch_bounds__(256) void pack_weights(
    const float* __restrict__ W0, const float* __restrict__ W2,
    const float* __restrict__ W3, _Float16* __restrict__ ws)
{
    const int g = blockIdx.x * 256 + threadIdx.x;   // fragment group id
    if (g >= 4608) return;

    const float* src;
    int ks, ct, lg, lr, ncol, kmax;
    long hoff, loff;
    if (g < 512) {                       // W0: [2][4][4][16]
        ks = g >> 8; ct = (g >> 6) & 3; lg = (g >> 4) & 3; lr = g & 15;
        src = W0; ncol = 64; kmax = 40;
        hoff = (long)g * 8;  loff = hoff + 4096;
    } else if (g < 2560) {               // W2: [4][8][4][16]
        int gg = g - 512;
        ks = gg >> 9; ct = (gg >> 6) & 7; lg = (gg >> 4) & 3; lr = gg & 15;
        src = W2; ncol = 128; kmax = 128;
        hoff = 8192 + (long)gg * 8; loff = hoff + 16384;
    } else {                             // W3: [4][8][4][16]
        int gg = g - 2560;
        ks = gg >> 9; ct = (gg >> 6) & 7; lg = (gg >> 4) & 3; lr = gg & 15;
        src = W3; ncol = 128; kmax = 128;
        hoff = 40960 + (long)gg * 8; loff = hoff + 16384;
    }

    f16x8 hi, lo;
#pragma unroll
    for (int e = 0; e < 8; ++e) {
        const int k = ks * 32 + lg * 8 + e;
        const float v = (k < kmax) ? src[(long)k * ncol + ct * 16 + lr] : 0.f;
        _Float16 h = (_Float16)v;
        hi[e] = h;
        lo[e] = (_Float16)(v - (float)h);
    }
    *reinterpret_cast<f16x8*>(ws + hoff) = hi;
    *reinterpret_cast<f16x8*>(ws + loff) = lo;
}

__global__ __launch_bounds__(64, 4) void critic_attention_kernel(
    const float* __restrict__ obs, const float* __restrict__ act,
    const float* __restrict__ b0, const float* __restrict__ W1,
    const float* __restrict__ b1v, const float* __restrict__ b2,
    const float* __restrict__ b3, const float* __restrict__ Wc,
    const float* __restrict__ bcv, const _Float16* __restrict__ ws,
    float* __restrict__ out)
{
    __shared__ float xcat[16 * 132];   // one wave's 16 items; stride 132 = 16B-aligned

    const int lane = threadIdx.x;      // 0..63
    const int lr = lane & 15;          // item row (A) / D-col
    const int lg = lane >> 4;          // k-chunk / D-row-group

    const long ibase = (long)blockIdx.x * 16;

    // W0 fragments from ws (stay in regs through the agent loop)
    f16x8 w0h[2][4], w0l[2][4];
#pragma unroll
    for (int ks = 0; ks < 2; ++ks)
#pragma unroll
        for (int ct = 0; ct < 4; ++ct) {
            const long o = (((long)(ks * 4 + ct) * 4 + lg) * 16 + lr) * 8;
            w0h[ks][ct] = *reinterpret_cast<const f16x8*>(ws + o);
            w0l[ks][ct] = *reinterpret_cast<const f16x8*>(ws + 4096 + o);
        }

    float b0c[4], W1sc[4], W1oc[4];
#pragma unroll
    for (int ct = 0; ct < 4; ++ct) {
        b0c[ct]  = b0[ct * 16 + lr];
        W1sc[ct] = W1[ct * 16 + lr];
        W1oc[ct] = W1[64 + ct * 16 + lr];
    }
    const float b1s = b1v[0];

    const float* obase = obs + (ibase + lr) * 512 + lg * 8;   // this lane's item row
    const float* abase = act + (ibase + lr) * 128;            // lg==0 lanes only

    float4 q0 = *reinterpret_cast<const float4*>(obase);
    float4 q1 = *reinterpret_cast<const float4*>(obase + 4);
    float4 c0 = make_float4(0.f, 0.f, 0.f, 0.f), c1 = c0;
    if (lg == 0) {
        c0 = *reinterpret_cast<const float4*>(abase);
        c1 = *reinterpret_cast<const float4*>(abase + 4);
    }

    // ---------------- agent 0 (self) ----------------
    float a_self[4], s[4], xsum[4][4];
    {
        float a0f[8] = {q0.x, q0.y, q0.z, q0.w, q1.x, q1.y, q1.z, q1.w};
        float a1f[8] = {c0.x, c0.y, c0.z, c0.w, c1.x, c1.y, c1.z, c1.w};
        f16x8 ah0 = cvt8(a0f);
        f16x8 ah1 = cvt8(a1f);

        // prefetch agent 1
        q0 = *reinterpret_cast<const float4*>(obase + 32);
        q1 = *reinterpret_cast<const float4*>(obase + 36);
        if (lg == 0) {
            c0 = *reinterpret_cast<const float4*>(abase + 8);
            c1 = *reinterpret_cast<const float4*>(abase + 12);
        }

        f32x4 acc[4];
#pragma unroll
        for (int ct = 0; ct < 4; ++ct) {
            acc[ct] = (f32x4){b0c[ct], b0c[ct], b0c[ct], b0c[ct]};  // bias folded
            acc[ct] = MFMA(ah0, w0l[0][ct], acc[ct]);
            acc[ct] = MFMA(ah0, w0h[0][ct], acc[ct]);
            acc[ct] = MFMA(ah1, w0l[1][ct], acc[ct]);
            acc[ct] = MFMA(ah1, w0h[1][ct], acc[ct]);
        }

        float xa[4][4], p[4];
#pragma unroll
        for (int j = 0; j < 4; ++j) {
#pragma unroll
            for (int ct = 0; ct < 4; ++ct)
                xa[ct][j] = lrelu(acc[ct][j]);
            p[j] = xa[0][j] * W1sc[0];
            p[j] = fmaf(xa[1][j], W1sc[1], p[j]);
            p[j] = fmaf(xa[2][j], W1sc[2], p[j]);
            p[j] = fmaf(xa[3][j], W1sc[3], p[j]);
            p[j] += __shfl_xor(p[j], 1, 64);
            p[j] += __shfl_xor(p[j], 2, 64);
            p[j] += __shfl_xor(p[j], 4, 64);
            p[j] += __shfl_xor(p[j], 8, 64);
            a_self[j] = b1s + p[j];
            s[j] = 0.f;
#pragma unroll
            for (int ct = 0; ct < 4; ++ct) xsum[ct][j] = 0.f;
        }
#pragma unroll
        for (int ct = 0; ct < 4; ++ct)
#pragma unroll
            for (int j = 0; j < 4; ++j)
                xcat[(lg * 4 + j) * 132 + ct * 16 + lr] = xa[ct][j];   // x_self
    }

    // ---------------- agents 1..15: no-max softmax, rolled loop ----------------
    for (int a = 1; a < 16; ++a) {
        float a0f[8] = {q0.x, q0.y, q0.z, q0.w, q1.x, q1.y, q1.z, q1.w};
        float a1f[8] = {c0.x, c0.y, c0.z, c0.w, c1.x, c1.y, c1.z, c1.w};
        f16x8 ah0 = cvt8(a0f);
        f16x8 ah1 = cvt8(a1f);

        if (a < 15) {   // prefetch next agent
            q0 = *reinterpret_cast<const float4*>(obase + (a + 1) * 32);
            q1 = *reinterpret_cast<const float4*>(obase + (a + 1) * 32 + 4);
            if (lg == 0) {
                c0 = *reinterpret_cast<const float4*>(abase + (a + 1) * 8);
                c1 = *reinterpret_cast<const float4*>(abase + (a + 1) * 8 + 4);
            }
        }

        f32x4 acc[4];
#pragma unroll
        for (int ct = 0; ct < 4; ++ct) {
            acc[ct] = (f32x4){b0c[ct], b0c[ct], b0c[ct], b0c[ct]};  // bias folded
            acc[ct] = MFMA(ah0, w0l[0][ct], acc[ct]);
            acc[ct] = MFMA(ah0, w0h[0][ct], acc[ct]);
            acc[ct] = MFMA(ah1, w0l[1][ct], acc[ct]);
            acc[ct] = MFMA(ah1, w0h[1][ct], acc[ct]);
        }

        float xa[4][4], p[4];
#pragma unroll
        for (int j = 0; j < 4; ++j) {
#pragma unroll
            for (int ct = 0; ct < 4; ++ct)
                xa[ct][j] = fast_tanh(acc[ct][j]);
            p[j] = xa[0][j] * W1oc[0];
            p[j] = fmaf(xa[1][j], W1oc[1], p[j]);
            p[j] = fmaf(xa[2][j], W1oc[2], p[j]);
            p[j] = fmaf(xa[3][j], W1oc[3], p[j]);
            p[j] += __shfl_xor(p[j], 1, 64);
            p[j] += __shfl_xor(p[j], 2, 64);
            p[j] += __shfl_xor(p[j], 4, 64);
            p[j] += __shfl_xor(p[j], 8, 64);
        }
        // bounded logits -> softmax without max-subtraction, pure accumulation
#pragma unroll
        for (int j = 0; j < 4; ++j) {
            const float e = exp2f(lrelu(a_self[j] + p[j]) * LOG2E);
            s[j] += e;
#pragma unroll
            for (int ct = 0; ct < 4; ++ct)
                xsum[ct][j] = fmaf(e, xa[ct][j], xsum[ct][j]);
        }
    }

    // x_sum -> LDS
#pragma unroll
    for (int j = 0; j < 4; ++j) {
        const float inv = __fdividef(1.f, s[j]);
#pragma unroll
        for (int ct = 0; ct < 4; ++ct)
            xcat[(lg * 4 + j) * 132 + 64 + ct * 16 + lr] = xsum[ct][j] * inv;
    }

    // ---------------- phase B: x_cat[16x128] @ W2 -> x1 -> @ W3 -> x2 -> Wc ----------------
    float b2c[8], b3c[8], Wcc[8];
#pragma unroll
    for (int ct = 0; ct < 8; ++ct) {
        b2c[ct] = b2[ct * 16 + lr];
        b3c[ct] = b3[ct * 16 + lr];
        Wcc[ct] = Wc[ct * 16 + lr];
    }
    const float bcs = bcv[0];

    f32x4 acc2[8];
#pragma unroll
    for (int ct = 0; ct < 8; ++ct)
        acc2[ct] = (f32x4){b2c[ct], b2c[ct], b2c[ct], b2c[ct]};   // bias folded
#pragma unroll
    for (int ks = 0; ks < 4; ++ks) {
        const float* xr = xcat + lr * 132 + ks * 32 + lg * 8;
        float4 r0 = *reinterpret_cast<const float4*>(xr);
        float4 r1 = *reinterpret_cast<const float4*>(xr + 4);
        float av[8] = {r0.x, r0.y, r0.z, r0.w, r1.x, r1.y, r1.z, r1.w};
        f16x8 ah, al;
        split8(av, ah, al);
#pragma unroll
        for (int ct = 0; ct < 8; ++ct) {
            const long gg = ((long)(ks * 8 + ct) * 4 + lg) * 16 + lr;
            f16x8 bh = *reinterpret_cast<const f16x8*>(ws + 8192 + gg * 8);
            f16x8 bl = *reinterpret_cast<const f16x8*>(ws + 24576 + gg * 8);
            acc2[ct] = MFMA(al, bh, acc2[ct]);
            acc2[ct] = MFMA(ah, bl, acc2[ct]);
            acc2[ct] = MFMA(ah, bh, acc2[ct]);
        }
    }
#pragma unroll
    for (int ct = 0; ct < 8; ++ct)
#pragma unroll
        for (int j = 0; j < 4; ++j)
            xcat[(lg * 4 + j) * 132 + ct * 16 + lr] = lrelu(acc2[ct][j]);

#pragma unroll
    for (int ct = 0; ct < 8; ++ct)
        acc2[ct] = (f32x4){b3c[ct], b3c[ct], b3c[ct], b3c[ct]};   // bias folded
#pragma unroll
    for (int ks = 0; ks < 4; ++ks) {
        const float* xr = xcat + lr * 132 + ks * 32 + lg * 8;
        float4 r0 = *reinterpret_cast<const float4*>(xr);
        float4 r1 = *reinterpret_cast<const float4*>(xr + 4);
        float av[8] = {r0.x, r0.y, r0.z, r0.w, r1.x, r1.y, r1.z, r1.w};
        f16x8 ah, al;
        split8(av, ah, al);
#pragma unroll
        for (int ct = 0; ct < 8; ++ct) {
            const long gg = ((long)(ks * 8 + ct) * 4 + lg) * 16 + lr;
            f16x8 bh = *reinterpret_cast<const f16x8*>(ws + 40960 + gg * 8);
            f16x8 bl = *reinterpret_cast<const f16x8*>(ws + 57344 + gg * 8);
            acc2[ct] = MFMA(al, bh, acc2[ct]);
            acc2[ct] = MFMA(ah, bl, acc2[ct]);
            acc2[ct] = MFMA(ah, bh, acc2[ct]);
        }
    }

    // value: per-lane col partials, butterfly over the 16 cols
    float v[4];
#pragma unroll
    for (int j = 0; j < 4; ++j) {
        v[j] = lrelu(acc2[0][j]) * Wcc[0];
#pragma unroll
        for (int ct = 1; ct < 8; ++ct)
            v[j] = fmaf(lrelu(acc2[ct][j]), Wcc[ct], v[j]);
        v[j] += __shfl_xor(v[j], 1, 64);
        v[j] += __shfl_xor(v[j], 2, 64);
        v[j] += __shfl_xor(v[j], 4, 64);
        v[j] += __shfl_xor(v[j], 8, 64);
    }
    if (lr == 0) {
#pragma unroll
        for (int j = 0; j < 4; ++j)
            out[ibase + lg * 4 + j] = v[j] + bcs;
    }
}

extern "C" void kernel_launch(void* const* d_in, const int* in_sizes, int n_in,
                              void* d_out, int out_size, void* d_ws, size_t ws_size,
                              hipStream_t stream) {
    (void)in_sizes; (void)n_in; (void)ws_size; (void)out_size;
    const float* obs = (const float*)d_in[0];
    const float* act = (const float*)d_in[1];
    const float* W0  = (const float*)d_in[2];
    const float* b0  = (const float*)d_in[3];
    const float* W1  = (const float*)d_in[4];
    const float* b1  = (const float*)d_in[5];
    const float* W2  = (const float*)d_in[6];
    const float* b2  = (const float*)d_in[7];
    const float* W3  = (const float*)d_in[8];
    const float* b3  = (const float*)d_in[9];
    const float* Wc  = (const float*)d_in[10];
    const float* bc  = (const float*)d_in[11];
    _Float16* ws = (_Float16*)d_ws;

    pack_weights<<<dim3(18), dim3(256), 0, stream>>>(W0, W2, W3, ws);
    critic_attention_kernel<<<dim3(65536 / 16), dim3(64), 0, stream>>>(
        obs, act, b0, W1, b1, b2, b3, Wc, bc, ws, (float*)d_out);
}

// Round 11
// 88.345 us; speedup vs baseline: 2.4550x; 2.4550x over previous
//
#include <hip/hip_runtime.h>
#include <math.h>

// critic_attention, round 11: round-10 kernel with the VGPR cap fixed.
// Round 10's __launch_bounds__(64,4) capped VGPR at 64 -> the 16 f16x8 W0
// fragments couldn't stay resident -> compiler re-streamed them from memory
// every agent iteration (FETCH 83->500 MB, dur 94->217us). This kernel: cap
// 256 (64,2); allocator lands ~100 VGPR as in round 8 (same live state).
// Kept from rounds 9/10 (validated register-neutral VALU cuts):
//  (a) A-operand single fp16 (weights hi/lo split): D = Ah*Bl + Ah*Bh.
//  (b) biases folded into MFMA accumulator init.
//  (c) rolled agent loop, depth-1 rolling prefetch (round 8's 100-VGPR shape).
//
// Fragment conventions (m89-verified, validated rounds 6-10):
//   A-frag: lane holds row (l&15), k = (l>>4)*8 + e
//   B-frag: lane holds col (l&15), k = (l>>4)*8 + e
//   D:      lane holds col (l&15), row = (l>>4)*4 + reg
//
// ws layout (halfs): W0h@0[2][4][4][16][8] W0l@4096 | W2h@8192[4][8][4][16][8]
//   W2l@24576 | W3h@40960 W3l@57344.  Total 73728 halfs = 147456 B.

#define SLOPE 0.01f
#define LOG2E 1.4426950408889634f

typedef _Float16 f16x8 __attribute__((ext_vector_type(8)));
typedef float f32x4 __attribute__((ext_vector_type(4)));

#define MFMA(a, b, c) __builtin_amdgcn_mfma_f32_16x16x32_f16((a), (b), (c), 0, 0, 0)

__device__ __forceinline__ float lrelu(float x) { return fmaxf(x, SLOPE * x); }

__device__ __forceinline__ float fast_tanh(float x) {
    float e = exp2f(x * (2.0f * LOG2E));
    float r = __fdividef(1.0f, e + 1.0f);
    return fmaf(-2.0f, r, 1.0f);
}

__device__ __forceinline__ f16x8 cvt8(const float f[8]) {
    f16x8 r;
#pragma unroll
    for (int e = 0; e < 8; ++e) r[e] = (_Float16)f[e];
    return r;
}

__device__ __forceinline__ void split8(const float f[8], f16x8& hi, f16x8& lo) {
#pragma unroll
    for (int e = 0; e < 8; ++e) {
        _Float16 h = (_Float16)f[e];
        hi[e] = h;
        lo[e] = (_Float16)(f[e] - (float)h);
    }
}

// ---------------- prep: split weights into per-lane fp16 hi/lo fragments ----------------
__global__ __launch_bounds__(256) void pack_weights(
    const float* __restrict__ W0, const float* __restrict__ W2,
    const float* __restrict__ W3, _Float16* __restrict__ ws)
{
    const int g = blockIdx.x * 256 + threadIdx.x;   // fragment group id
    if (g >= 4608) return;

    const float* src;
    int ks, ct, lg, lr, ncol, kmax;
    long hoff, loff;
    if (g < 512) {                       // W0: [2][4][4][16]
        ks = g >> 8; ct = (g >> 6) & 3; lg = (g >> 4) & 3; lr = g & 15;
        src = W0; ncol = 64; kmax = 40;
        hoff = (long)g * 8;  loff = hoff + 4096;
    } else if (g < 2560) {               // W2: [4][8][4][16]
        int gg = g - 512;
        ks = gg >> 9; ct = (gg >> 6) & 7; lg = (gg >> 4) & 3; lr = gg & 15;
        src = W2; ncol = 128; kmax = 128;
        hoff = 8192 + (long)gg * 8; loff = hoff + 16384;
    } else {                             // W3: [4][8][4][16]
        int gg = g - 2560;
        ks = gg >> 9; ct = (gg >> 6) & 7; lg = (gg >> 4) & 3; lr = gg & 15;
        src = W3; ncol = 128; kmax = 128;
        hoff = 40960 + (long)gg * 8; loff = hoff + 16384;
    }

    f16x8 hi, lo;
#pragma unroll
    for (int e = 0; e < 8; ++e) {
        const int k = ks * 32 + lg * 8 + e;
        const float v = (k < kmax) ? src[(long)k * ncol + ct * 16 + lr] : 0.f;
        _Float16 h = (_Float16)v;
        hi[e] = h;
        lo[e] = (_Float16)(v - (float)h);
    }
    *reinterpret_cast<f16x8*>(ws + hoff) = hi;
    *reinterpret_cast<f16x8*>(ws + loff) = lo;
}

__global__ __launch_bounds__(64, 2) void critic_attention_kernel(
    const float* __restrict__ obs, const float* __restrict__ act,
    const float* __restrict__ b0, const float* __restrict__ W1,
    const float* __restrict__ b1v, const float* __restrict__ b2,
    const float* __restrict__ b3, const float* __restrict__ Wc,
    const float* __restrict__ bcv, const _Float16* __restrict__ ws,
    float* __restrict__ out)
{
    __shared__ float xcat[16 * 132];   // one wave's 16 items; stride 132 = 16B-aligned

    const int lane = threadIdx.x;      // 0..63
    const int lr = lane & 15;          // item row (A) / D-col
    const int lg = lane >> 4;          // k-chunk / D-row-group

    const long ibase = (long)blockIdx.x * 16;

    // W0 fragments from ws (stay in regs through the agent loop)
    f16x8 w0h[2][4], w0l[2][4];
#pragma unroll
    for (int ks = 0; ks < 2; ++ks)
#pragma unroll
        for (int ct = 0; ct < 4; ++ct) {
            const long o = (((long)(ks * 4 + ct) * 4 + lg) * 16 + lr) * 8;
            w0h[ks][ct] = *reinterpret_cast<const f16x8*>(ws + o);
            w0l[ks][ct] = *reinterpret_cast<const f16x8*>(ws + 4096 + o);
        }

    float b0c[4], W1sc[4], W1oc[4];
#pragma unroll
    for (int ct = 0; ct < 4; ++ct) {
        b0c[ct]  = b0[ct * 16 + lr];
        W1sc[ct] = W1[ct * 16 + lr];
        W1oc[ct] = W1[64 + ct * 16 + lr];
    }
    const float b1s = b1v[0];

    const float* obase = obs + (ibase + lr) * 512 + lg * 8;   // this lane's item row
    const float* abase = act + (ibase + lr) * 128;            // lg==0 lanes only

    float4 q0 = *reinterpret_cast<const float4*>(obase);
    float4 q1 = *reinterpret_cast<const float4*>(obase + 4);
    float4 c0 = make_float4(0.f, 0.f, 0.f, 0.f), c1 = c0;
    if (lg == 0) {
        c0 = *reinterpret_cast<const float4*>(abase);
        c1 = *reinterpret_cast<const float4*>(abase + 4);
    }

    // ---------------- agent 0 (self) ----------------
    float a_self[4], s[4], xsum[4][4];
    {
        float a0f[8] = {q0.x, q0.y, q0.z, q0.w, q1.x, q1.y, q1.z, q1.w};
        float a1f[8] = {c0.x, c0.y, c0.z, c0.w, c1.x, c1.y, c1.z, c1.w};
        f16x8 ah0 = cvt8(a0f);
        f16x8 ah1 = cvt8(a1f);

        // prefetch agent 1
        q0 = *reinterpret_cast<const float4*>(obase + 32);
        q1 = *reinterpret_cast<const float4*>(obase + 36);
        if (lg == 0) {
            c0 = *reinterpret_cast<const float4*>(abase + 8);
            c1 = *reinterpret_cast<const float4*>(abase + 12);
        }

        f32x4 acc[4];
#pragma unroll
        for (int ct = 0; ct < 4; ++ct) {
            acc[ct] = (f32x4){b0c[ct], b0c[ct], b0c[ct], b0c[ct]};  // bias folded
            acc[ct] = MFMA(ah0, w0l[0][ct], acc[ct]);
            acc[ct] = MFMA(ah0, w0h[0][ct], acc[ct]);
            acc[ct] = MFMA(ah1, w0l[1][ct], acc[ct]);
            acc[ct] = MFMA(ah1, w0h[1][ct], acc[ct]);
        }

        float xa[4][4], p[4];
#pragma unroll
        for (int j = 0; j < 4; ++j) {
#pragma unroll
            for (int ct = 0; ct < 4; ++ct)
                xa[ct][j] = lrelu(acc[ct][j]);
            p[j] = xa[0][j] * W1sc[0];
            p[j] = fmaf(xa[1][j], W1sc[1], p[j]);
            p[j] = fmaf(xa[2][j], W1sc[2], p[j]);
            p[j] = fmaf(xa[3][j], W1sc[3], p[j]);
            p[j] += __shfl_xor(p[j], 1, 64);
            p[j] += __shfl_xor(p[j], 2, 64);
            p[j] += __shfl_xor(p[j], 4, 64);
            p[j] += __shfl_xor(p[j], 8, 64);
            a_self[j] = b1s + p[j];
            s[j] = 0.f;
#pragma unroll
            for (int ct = 0; ct < 4; ++ct) xsum[ct][j] = 0.f;
        }
#pragma unroll
        for (int ct = 0; ct < 4; ++ct)
#pragma unroll
            for (int j = 0; j < 4; ++j)
                xcat[(lg * 4 + j) * 132 + ct * 16 + lr] = xa[ct][j];   // x_self
    }

    // ---------------- agents 1..15: no-max softmax, rolled loop ----------------
    for (int a = 1; a < 16; ++a) {
        float a0f[8] = {q0.x, q0.y, q0.z, q0.w, q1.x, q1.y, q1.z, q1.w};
        float a1f[8] = {c0.x, c0.y, c0.z, c0.w, c1.x, c1.y, c1.z, c1.w};
        f16x8 ah0 = cvt8(a0f);
        f16x8 ah1 = cvt8(a1f);

        if (a < 15) {   // prefetch next agent
            q0 = *reinterpret_cast<const float4*>(obase + (a + 1) * 32);
            q1 = *reinterpret_cast<const float4*>(obase + (a + 1) * 32 + 4);
            if (lg == 0) {
                c0 = *reinterpret_cast<const float4*>(abase + (a + 1) * 8);
                c1 = *reinterpret_cast<const float4*>(abase + (a + 1) * 8 + 4);
            }
        }

        f32x4 acc[4];
#pragma unroll
        for (int ct = 0; ct < 4; ++ct) {
            acc[ct] = (f32x4){b0c[ct], b0c[ct], b0c[ct], b0c[ct]};  // bias folded
            acc[ct] = MFMA(ah0, w0l[0][ct], acc[ct]);
            acc[ct] = MFMA(ah0, w0h[0][ct], acc[ct]);
            acc[ct] = MFMA(ah1, w0l[1][ct], acc[ct]);
            acc[ct] = MFMA(ah1, w0h[1][ct], acc[ct]);
        }

        float xa[4][4], p[4];
#pragma unroll
        for (int j = 0; j < 4; ++j) {
#pragma unroll
            for (int ct = 0; ct < 4; ++ct)
                xa[ct][j] = fast_tanh(acc[ct][j]);
            p[j] = xa[0][j] * W1oc[0];
            p[j] = fmaf(xa[1][j], W1oc[1], p[j]);
            p[j] = fmaf(xa[2][j], W1oc[2], p[j]);
            p[j] = fmaf(xa[3][j], W1oc[3], p[j]);
            p[j] += __shfl_xor(p[j], 1, 64);
            p[j] += __shfl_xor(p[j], 2, 64);
            p[j] += __shfl_xor(p[j], 4, 64);
            p[j] += __shfl_xor(p[j], 8, 64);
        }
        // bounded logits -> softmax without max-subtraction, pure accumulation
#pragma unroll
        for (int j = 0; j < 4; ++j) {
            const float e = exp2f(lrelu(a_self[j] + p[j]) * LOG2E);
            s[j] += e;
#pragma unroll
            for (int ct = 0; ct < 4; ++ct)
                xsum[ct][j] = fmaf(e, xa[ct][j], xsum[ct][j]);
        }
    }

    // x_sum -> LDS
#pragma unroll
    for (int j = 0; j < 4; ++j) {
        const float inv = __fdividef(1.f, s[j]);
#pragma unroll
        for (int ct = 0; ct < 4; ++ct)
            xcat[(lg * 4 + j) * 132 + 64 + ct * 16 + lr] = xsum[ct][j] * inv;
    }

    // ---------------- phase B: x_cat[16x128] @ W2 -> x1 -> @ W3 -> x2 -> Wc ----------------
    float b2c[8], b3c[8], Wcc[8];
#pragma unroll
    for (int ct = 0; ct < 8; ++ct) {
        b2c[ct] = b2[ct * 16 + lr];
        b3c[ct] = b3[ct * 16 + lr];
        Wcc[ct] = Wc[ct * 16 + lr];
    }
    const float bcs = bcv[0];

    f32x4 acc2[8];
#pragma unroll
    for (int ct = 0; ct < 8; ++ct)
        acc2[ct] = (f32x4){b2c[ct], b2c[ct], b2c[ct], b2c[ct]};   // bias folded
#pragma unroll
    for (int ks = 0; ks < 4; ++ks) {
        const float* xr = xcat + lr * 132 + ks * 32 + lg * 8;
        float4 r0 = *reinterpret_cast<const float4*>(xr);
        float4 r1 = *reinterpret_cast<const float4*>(xr + 4);
        float av[8] = {r0.x, r0.y, r0.z, r0.w, r1.x, r1.y, r1.z, r1.w};
        f16x8 ah, al;
        split8(av, ah, al);
#pragma unroll
        for (int ct = 0; ct < 8; ++ct) {
            const long gg = ((long)(ks * 8 + ct) * 4 + lg) * 16 + lr;
            f16x8 bh = *reinterpret_cast<const f16x8*>(ws + 8192 + gg * 8);
            f16x8 bl = *reinterpret_cast<const f16x8*>(ws + 24576 + gg * 8);
            acc2[ct] = MFMA(al, bh, acc2[ct]);
            acc2[ct] = MFMA(ah, bl, acc2[ct]);
            acc2[ct] = MFMA(ah, bh, acc2[ct]);
        }
    }
#pragma unroll
    for (int ct = 0; ct < 8; ++ct)
#pragma unroll
        for (int j = 0; j < 4; ++j)
            xcat[(lg * 4 + j) * 132 + ct * 16 + lr] = lrelu(acc2[ct][j]);

#pragma unroll
    for (int ct = 0; ct < 8; ++ct)
        acc2[ct] = (f32x4){b3c[ct], b3c[ct], b3c[ct], b3c[ct]};   // bias folded
#pragma unroll
    for (int ks = 0; ks < 4; ++ks) {
        const float* xr = xcat + lr * 132 + ks * 32 + lg * 8;
        float4 r0 = *reinterpret_cast<const float4*>(xr);
        float4 r1 = *reinterpret_cast<const float4*>(xr + 4);
        float av[8] = {r0.x, r0.y, r0.z, r0.w, r1.x, r1.y, r1.z, r1.w};
        f16x8 ah, al;
        split8(av, ah, al);
#pragma unroll
        for (int ct = 0; ct < 8; ++ct) {
            const long gg = ((long)(ks * 8 + ct) * 4 + lg) * 16 + lr;
            f16x8 bh = *reinterpret_cast<const f16x8*>(ws + 40960 + gg * 8);
            f16x8 bl = *reinterpret_cast<const f16x8*>(ws + 57344 + gg * 8);
            acc2[ct] = MFMA(al, bh, acc2[ct]);
            acc2[ct] = MFMA(ah, bl, acc2[ct]);
            acc2[ct] = MFMA(ah, bh, acc2[ct]);
        }
    }

    // value: per-lane col partials, butterfly over the 16 cols
    float v[4];
#pragma unroll
    for (int j = 0; j < 4; ++j) {
        v[j] = lrelu(acc2[0][j]) * Wcc[0];
#pragma unroll
        for (int ct = 1; ct < 8; ++ct)
            v[j] = fmaf(lrelu(acc2[ct][j]), Wcc[ct], v[j]);
        v[j] += __shfl_xor(v[j], 1, 64);
        v[j] += __shfl_xor(v[j], 2, 64);
        v[j] += __shfl_xor(v[j], 4, 64);
        v[j] += __shfl_xor(v[j], 8, 64);
    }
    if (lr == 0) {
#pragma unroll
        for (int j = 0; j < 4; ++j)
            out[ibase + lg * 4 + j] = v[j] + bcs;
    }
}

extern "C" void kernel_launch(void* const* d_in, const int* in_sizes, int n_in,
                              void* d_out, int out_size, void* d_ws, size_t ws_size,
                              hipStream_t stream) {
    (void)in_sizes; (void)n_in; (void)ws_size; (void)out_size;
    const float* obs = (const float*)d_in[0];
    const float* act = (const float*)d_in[1];
    const float* W0  = (const float*)d_in[2];
    const float* b0  = (const float*)d_in[3];
    const float* W1  = (const float*)d_in[4];
    const float* b1  = (const float*)d_in[5];
    const float* W2  = (const float*)d_in[6];
    const float* b2  = (const float*)d_in[7];
    const float* W3  = (const float*)d_in[8];
    const float* b3  = (const float*)d_in[9];
    const float* Wc  = (const float*)d_in[10];
    const float* bc  = (const float*)d_in[11];
    _Float16* ws = (_Float16*)d_ws;

    pack_weights<<<dim3(18), dim3(256), 0, stream>>>(W0, W2, W3, ws);
    critic_attention_kernel<<<dim3(65536 / 16), dim3(64), 0, stream>>>(
        obs, act, b0, W1, b1, b2, b3, Wc, bc, ws, (float*)d_out);
}

// Round 12
// 87.966 us; speedup vs baseline: 2.4655x; 1.0043x over previous
//
#include <hip/hip_runtime.h>
#include <math.h>

// critic_attention, round 12: 2-wave blocks, agent-split phase A.
// Round 11 evidence: occupancy pinned at 20% (grid = 4096 one-wave blocks =
// 4 waves/SIMD scheduled, 1.6 resident) while VGPR (92) would allow 5 resident.
// Fix: block = 2 waves on ONE 16-item tile. Wave 0: agents 0..7 (+ x_self,
// a_self); wave 1: agent 0 recomputed locally (identical FLOPs -> identical
// a_self, no mid-loop barrier) + agents 8..15. No-max softmax partials merge
// associatively through LDS (xsum[16x64] + s[16], 2 barriers). Phase B split
// by cols: wave w owns cols [w*64, w*64+64) of W2/W3/Wc (48 MFMA/layer/wave),
// barriers around the in-place x1 write. 8192 waves = 8/SIMD scheduled,
// ~5 resident; per-wave critical path ~halved.
//
// Fragment conventions (m89-verified, validated rounds 6-11):
//   A-frag: lane holds row (l&15), k = (l>>4)*8 + e
//   B-frag: lane holds col (l&15), k = (l>>4)*8 + e
//   D:      lane holds col (l&15), row = (l>>4)*4 + reg
//
// ws layout (halfs): W0h@0[2][4][4][16][8] W0l@4096 | W2h@8192[4][8][4][16][8]
//   W2l@24576 | W3h@40960 W3l@57344.  Total 73728 halfs = 147456 B.

#define SLOPE 0.01f
#define LOG2E 1.4426950408889634f

typedef _Float16 f16x8 __attribute__((ext_vector_type(8)));
typedef float f32x4 __attribute__((ext_vector_type(4)));

#define MFMA(a, b, c) __builtin_amdgcn_mfma_f32_16x16x32_f16((a), (b), (c), 0, 0, 0)

__device__ __forceinline__ float lrelu(float x) { return fmaxf(x, SLOPE * x); }

__device__ __forceinline__ float fast_tanh(float x) {
    float e = exp2f(x * (2.0f * LOG2E));
    float r = __fdividef(1.0f, e + 1.0f);
    return fmaf(-2.0f, r, 1.0f);
}

__device__ __forceinline__ f16x8 cvt8(const float f[8]) {
    f16x8 r;
#pragma unroll
    for (int e = 0; e < 8; ++e) r[e] = (_Float16)f[e];
    return r;
}

__device__ __forceinline__ void split8(const float f[8], f16x8& hi, f16x8& lo) {
#pragma unroll
    for (int e = 0; e < 8; ++e) {
        _Float16 h = (_Float16)f[e];
        hi[e] = h;
        lo[e] = (_Float16)(f[e] - (float)h);
    }
}

// ---------------- prep: split weights into per-lane fp16 hi/lo fragments ----------------
__global__ __launch_bounds__(256) void pack_weights(
    const float* __restrict__ W0, const float* __restrict__ W2,
    const float* __restrict__ W3, _Float16* __restrict__ ws)
{
    const int g = blockIdx.x * 256 + threadIdx.x;   // fragment group id
    if (g >= 4608) return;

    const float* src;
    int ks, ct, lg, lr, ncol, kmax;
    long hoff, loff;
    if (g < 512) {                       // W0: [2][4][4][16]
        ks = g >> 8; ct = (g >> 6) & 3; lg = (g >> 4) & 3; lr = g & 15;
        src = W0; ncol = 64; kmax = 40;
        hoff = (long)g * 8;  loff = hoff + 4096;
    } else if (g < 2560) {               // W2: [4][8][4][16]
        int gg = g - 512;
        ks = gg >> 9; ct = (gg >> 6) & 7; lg = (gg >> 4) & 3; lr = gg & 15;
        src = W2; ncol = 128; kmax = 128;
        hoff = 8192 + (long)gg * 8; loff = hoff + 16384;
    } else {                             // W3: [4][8][4][16]
        int gg = g - 2560;
        ks = gg >> 9; ct = (gg >> 6) & 7; lg = (gg >> 4) & 3; lr = gg & 15;
        src = W3; ncol = 128; kmax = 128;
        hoff = 40960 + (long)gg * 8; loff = hoff + 16384;
    }

    f16x8 hi, lo;
#pragma unroll
    for (int e = 0; e < 8; ++e) {
        const int k = ks * 32 + lg * 8 + e;
        const float v = (k < kmax) ? src[(long)k * ncol + ct * 16 + lr] : 0.f;
        _Float16 h = (_Float16)v;
        hi[e] = h;
        lo[e] = (_Float16)(v - (float)h);
    }
    *reinterpret_cast<f16x8*>(ws + hoff) = hi;
    *reinterpret_cast<f16x8*>(ws + loff) = lo;
}

__global__ __launch_bounds__(128, 2) void critic_attention_kernel(
    const float* __restrict__ obs, const float* __restrict__ act,
    const float* __restrict__ b0, const float* __restrict__ W1,
    const float* __restrict__ b1v, const float* __restrict__ b2,
    const float* __restrict__ b3, const float* __restrict__ Wc,
    const float* __restrict__ bcv, const _Float16* __restrict__ ws,
    float* __restrict__ out)
{
    __shared__ float xcat[16 * 132];   // x_cat / x1, 16 items; stride 132 = 16B-aligned
    __shared__ float part[16 * 68];    // wave1 partial xsum (stride 68: 2-way alias)
    __shared__ float ps[16];           // wave1 partial s
    __shared__ float vpart[32];        // Wc partials per wave

    const int t = threadIdx.x;
    const int lane = t & 63;
    const int w = t >> 6;              // wave 0/1
    const int lr = lane & 15;          // item row (A) / D-col
    const int lg = lane >> 4;          // k-chunk / D-row-group

    const long ibase = (long)blockIdx.x * 16;

    // W0 fragments (resident through the agent loop)
    f16x8 w0h[2][4], w0l[2][4];
#pragma unroll
    for (int ks = 0; ks < 2; ++ks)
#pragma unroll
        for (int ct = 0; ct < 4; ++ct) {
            const long o = (((long)(ks * 4 + ct) * 4 + lg) * 16 + lr) * 8;
            w0h[ks][ct] = *reinterpret_cast<const f16x8*>(ws + o);
            w0l[ks][ct] = *reinterpret_cast<const f16x8*>(ws + 4096 + o);
        }

    float b0c[4], W1sc[4], W1oc[4];
#pragma unroll
    for (int ct = 0; ct < 4; ++ct) {
        b0c[ct]  = b0[ct * 16 + lr];
        W1sc[ct] = W1[ct * 16 + lr];
        W1oc[ct] = W1[64 + ct * 16 + lr];
    }
    const float b1s = b1v[0];

    const float* obase = obs + (ibase + lr) * 512 + lg * 8;   // this lane's item row
    const float* abase = act + (ibase + lr) * 128;            // lg==0 lanes only

    const int abeg = w ? 8 : 1;        // wave0: agents 1..7; wave1: agents 8..15
    const int aend = w ? 16 : 8;

    float4 q0 = *reinterpret_cast<const float4*>(obase);
    float4 q1 = *reinterpret_cast<const float4*>(obase + 4);
    float4 c0 = make_float4(0.f, 0.f, 0.f, 0.f), c1 = c0;
    if (lg == 0) {
        c0 = *reinterpret_cast<const float4*>(abase);
        c1 = *reinterpret_cast<const float4*>(abase + 4);
    }

    // ---------------- agent 0: both waves (wave1 only needs a_self) ----------------
    float a_self[4], s[4], xsum[4][4];
    {
        float a0f[8] = {q0.x, q0.y, q0.z, q0.w, q1.x, q1.y, q1.z, q1.w};
        float a1f[8] = {c0.x, c0.y, c0.z, c0.w, c1.x, c1.y, c1.z, c1.w};
        f16x8 ah0 = cvt8(a0f);
        f16x8 ah1 = cvt8(a1f);

        // prefetch this wave's first loop agent
        q0 = *reinterpret_cast<const float4*>(obase + abeg * 32);
        q1 = *reinterpret_cast<const float4*>(obase + abeg * 32 + 4);
        if (lg == 0) {
            c0 = *reinterpret_cast<const float4*>(abase + abeg * 8);
            c1 = *reinterpret_cast<const float4*>(abase + abeg * 8 + 4);
        }

        f32x4 acc[4];
#pragma unroll
        for (int ct = 0; ct < 4; ++ct) {
            acc[ct] = (f32x4){b0c[ct], b0c[ct], b0c[ct], b0c[ct]};  // bias folded
            acc[ct] = MFMA(ah0, w0l[0][ct], acc[ct]);
            acc[ct] = MFMA(ah0, w0h[0][ct], acc[ct]);
            acc[ct] = MFMA(ah1, w0l[1][ct], acc[ct]);
            acc[ct] = MFMA(ah1, w0h[1][ct], acc[ct]);
        }

        float xa[4][4], p[4];
#pragma unroll
        for (int j = 0; j < 4; ++j) {
#pragma unroll
            for (int ct = 0; ct < 4; ++ct)
                xa[ct][j] = lrelu(acc[ct][j]);
            p[j] = xa[0][j] * W1sc[0];
            p[j] = fmaf(xa[1][j], W1sc[1], p[j]);
            p[j] = fmaf(xa[2][j], W1sc[2], p[j]);
            p[j] = fmaf(xa[3][j], W1sc[3], p[j]);
            p[j] += __shfl_xor(p[j], 1, 64);
            p[j] += __shfl_xor(p[j], 2, 64);
            p[j] += __shfl_xor(p[j], 4, 64);
            p[j] += __shfl_xor(p[j], 8, 64);
            a_self[j] = b1s + p[j];
            s[j] = 0.f;
#pragma unroll
            for (int ct = 0; ct < 4; ++ct) xsum[ct][j] = 0.f;
        }
        if (w == 0) {
#pragma unroll
            for (int ct = 0; ct < 4; ++ct)
#pragma unroll
                for (int j = 0; j < 4; ++j)
                    xcat[(lg * 4 + j) * 132 + ct * 16 + lr] = xa[ct][j];   // x_self
        }
    }

    // ---------------- this wave's 7-8 "other" agents: no-max softmax ----------------
    for (int a = abeg; a < aend; ++a) {
        float a0f[8] = {q0.x, q0.y, q0.z, q0.w, q1.x, q1.y, q1.z, q1.w};
        float a1f[8] = {c0.x, c0.y, c0.z, c0.w, c1.x, c1.y, c1.z, c1.w};
        f16x8 ah0 = cvt8(a0f);
        f16x8 ah1 = cvt8(a1f);

        if (a + 1 < aend) {   // prefetch next agent
            q0 = *reinterpret_cast<const float4*>(obase + (a + 1) * 32);
            q1 = *reinterpret_cast<const float4*>(obase + (a + 1) * 32 + 4);
            if (lg == 0) {
                c0 = *reinterpret_cast<const float4*>(abase + (a + 1) * 8);
                c1 = *reinterpret_cast<const float4*>(abase + (a + 1) * 8 + 4);
            }
        }

        f32x4 acc[4];
#pragma unroll
        for (int ct = 0; ct < 4; ++ct) {
            acc[ct] = (f32x4){b0c[ct], b0c[ct], b0c[ct], b0c[ct]};  // bias folded
            acc[ct] = MFMA(ah0, w0l[0][ct], acc[ct]);
            acc[ct] = MFMA(ah0, w0h[0][ct], acc[ct]);
            acc[ct] = MFMA(ah1, w0l[1][ct], acc[ct]);
            acc[ct] = MFMA(ah1, w0h[1][ct], acc[ct]);
        }

        float xa[4][4], p[4];
#pragma unroll
        for (int j = 0; j < 4; ++j) {
#pragma unroll
            for (int ct = 0; ct < 4; ++ct)
                xa[ct][j] = fast_tanh(acc[ct][j]);
            p[j] = xa[0][j] * W1oc[0];
            p[j] = fmaf(xa[1][j], W1oc[1], p[j]);
            p[j] = fmaf(xa[2][j], W1oc[2], p[j]);
            p[j] = fmaf(xa[3][j], W1oc[3], p[j]);
            p[j] += __shfl_xor(p[j], 1, 64);
            p[j] += __shfl_xor(p[j], 2, 64);
            p[j] += __shfl_xor(p[j], 4, 64);
            p[j] += __shfl_xor(p[j], 8, 64);
        }
        // bounded logits -> softmax without max-subtraction, pure accumulation
#pragma unroll
        for (int j = 0; j < 4; ++j) {
            const float e = exp2f(lrelu(a_self[j] + p[j]) * LOG2E);
            s[j] += e;
#pragma unroll
            for (int ct = 0; ct < 4; ++ct)
                xsum[ct][j] = fmaf(e, xa[ct][j], xsum[ct][j]);
        }
    }

    // ---------------- merge wave1 partials into wave0, write x_sum ----------------
    if (w == 1) {
#pragma unroll
        for (int j = 0; j < 4; ++j) {
#pragma unroll
            for (int ct = 0; ct < 4; ++ct)
                part[(lg * 4 + j) * 68 + ct * 16 + lr] = xsum[ct][j];
            if (lr == 0) ps[lg * 4 + j] = s[j];
        }
    }
    __syncthreads();
    if (w == 0) {
#pragma unroll
        for (int j = 0; j < 4; ++j) {
            const float stot = s[j] + ps[lg * 4 + j];
            const float inv = __fdividef(1.f, stot);
#pragma unroll
            for (int ct = 0; ct < 4; ++ct)
                xcat[(lg * 4 + j) * 132 + 64 + ct * 16 + lr] =
                    (xsum[ct][j] + part[(lg * 4 + j) * 68 + ct * 16 + lr]) * inv;
        }
    }
    __syncthreads();

    // ---------------- phase B: wave w owns cols [w*64, w*64+64) ----------------
    float b2c[4], b3c[4], Wcc[4];
#pragma unroll
    for (int ct = 0; ct < 4; ++ct) {
        const int ctg = w * 4 + ct;
        b2c[ct] = b2[ctg * 16 + lr];
        b3c[ct] = b3[ctg * 16 + lr];
        Wcc[ct] = Wc[ctg * 16 + lr];
    }
    const float bcs = bcv[0];

    f32x4 acc2[4];
#pragma unroll
    for (int ct = 0; ct < 4; ++ct)
        acc2[ct] = (f32x4){b2c[ct], b2c[ct], b2c[ct], b2c[ct]};   // bias folded
#pragma unroll
    for (int ks = 0; ks < 4; ++ks) {
        const float* xr = xcat + lr * 132 + ks * 32 + lg * 8;
        float4 r0 = *reinterpret_cast<const float4*>(xr);
        float4 r1 = *reinterpret_cast<const float4*>(xr + 4);
        float av[8] = {r0.x, r0.y, r0.z, r0.w, r1.x, r1.y, r1.z, r1.w};
        f16x8 ah, al;
        split8(av, ah, al);
#pragma unroll
        for (int ct = 0; ct < 4; ++ct) {
            const int ctg = w * 4 + ct;
            const long gg = ((long)(ks * 8 + ctg) * 4 + lg) * 16 + lr;
            f16x8 bh = *reinterpret_cast<const f16x8*>(ws + 8192 + gg * 8);
            f16x8 bl = *reinterpret_cast<const f16x8*>(ws + 24576 + gg * 8);
            acc2[ct] = MFMA(al, bh, acc2[ct]);
            acc2[ct] = MFMA(ah, bl, acc2[ct]);
            acc2[ct] = MFMA(ah, bh, acc2[ct]);
        }
    }
    __syncthreads();   // all x_cat reads done before x1 overwrite
#pragma unroll
    for (int ct = 0; ct < 4; ++ct)
#pragma unroll
        for (int j = 0; j < 4; ++j)
            xcat[(lg * 4 + j) * 132 + (w * 4 + ct) * 16 + lr] = lrelu(acc2[ct][j]);
    __syncthreads();

#pragma unroll
    for (int ct = 0; ct < 4; ++ct)
        acc2[ct] = (f32x4){b3c[ct], b3c[ct], b3c[ct], b3c[ct]};   // bias folded
#pragma unroll
    for (int ks = 0; ks < 4; ++ks) {
        const float* xr = xcat + lr * 132 + ks * 32 + lg * 8;
        float4 r0 = *reinterpret_cast<const float4*>(xr);
        float4 r1 = *reinterpret_cast<const float4*>(xr + 4);
        float av[8] = {r0.x, r0.y, r0.z, r0.w, r1.x, r1.y, r1.z, r1.w};
        f16x8 ah, al;
        split8(av, ah, al);
#pragma unroll
        for (int ct = 0; ct < 4; ++ct) {
            const int ctg = w * 4 + ct;
            const long gg = ((long)(ks * 8 + ctg) * 4 + lg) * 16 + lr;
            f16x8 bh = *reinterpret_cast<const f16x8*>(ws + 40960 + gg * 8);
            f16x8 bl = *reinterpret_cast<const f16x8*>(ws + 57344 + gg * 8);
            acc2[ct] = MFMA(al, bh, acc2[ct]);
            acc2[ct] = MFMA(ah, bl, acc2[ct]);
            acc2[ct] = MFMA(ah, bh, acc2[ct]);
        }
    }

    // value: per-lane partials over this wave's 64 cols, butterfly over lr
    float v[4];
#pragma unroll
    for (int j = 0; j < 4; ++j) {
        v[j] = lrelu(acc2[0][j]) * Wcc[0];
#pragma unroll
        for (int ct = 1; ct < 4; ++ct)
            v[j] = fmaf(lrelu(acc2[ct][j]), Wcc[ct], v[j]);
        v[j] += __shfl_xor(v[j], 1, 64);
        v[j] += __shfl_xor(v[j], 2, 64);
        v[j] += __shfl_xor(v[j], 4, 64);
        v[j] += __shfl_xor(v[j], 8, 64);
    }
    if (lr == 0) {
#pragma unroll
        for (int j = 0; j < 4; ++j)
            vpart[w * 16 + lg * 4 + j] = v[j];
    }
    __syncthreads();
    if (w == 0 && lr == 0) {
#pragma unroll
        for (int j = 0; j < 4; ++j) {
            const int row = lg * 4 + j;
            out[ibase + row] = vpart[row] + vpart[16 + row] + bcs;
        }
    }
}

extern "C" void kernel_launch(void* const* d_in, const int* in_sizes, int n_in,
                              void* d_out, int out_size, void* d_ws, size_t ws_size,
                              hipStream_t stream) {
    (void)in_sizes; (void)n_in; (void)ws_size; (void)out_size;
    const float* obs = (const float*)d_in[0];
    const float* act = (const float*)d_in[1];
    const float* W0  = (const float*)d_in[2];
    const float* b0  = (const float*)d_in[3];
    const float* W1  = (const float*)d_in[4];
    const float* b1  = (const float*)d_in[5];
    const float* W2  = (const float*)d_in[6];
    const float* b2  = (const float*)d_in[7];
    const float* W3  = (const float*)d_in[8];
    const float* b3  = (const float*)d_in[9];
    const float* Wc  = (const float*)d_in[10];
    const float* bc  = (const float*)d_in[11];
    _Float16* ws = (_Float16*)d_ws;

    pack_weights<<<dim3(18), dim3(256), 0, stream>>>(W0, W2, W3, ws);
    critic_attention_kernel<<<dim3(65536 / 16), dim3(128), 0, stream>>>(
        obs, act, b0, W1, b1, b2, b3, Wc, bc, ws, (float*)d_out);
}